// Round 1
// baseline (1889.238 us; speedup 1.0000x reference)
//
#include <hip/hip_runtime.h>
#include <math.h>

typedef _Float16 f16;
typedef _Float16 f16x8 __attribute__((ext_vector_type(8)));
typedef float f32x4 __attribute__((ext_vector_type(4)));

#define TT 1024
#define HH 128
#define NG 512
#define ASTR 328   // A_s row stride in halves: 164 dwords -> bank group (41r+g)%8, 2 lanes/bank (free)
#define NEV 24

__device__ __forceinline__ float sigm(float x){ return 1.f/(1.f + __expf(-x)); }
__device__ __forceinline__ float tanh_f(float x){
    float ax = fabsf(x);
    float e = __expf(-2.f*ax);
    float r = (1.f - e)/(1.f + e);
    return (x < 0.f) ? -r : r;
}

// ---------------- prep: pack LSTM weights (f16, K-padded) + bias sum + transposed fsim weights ----------------
__global__ void pack_kernel(const float* __restrict__ W_ih, const float* __restrict__ W_hh,
                            const float* __restrict__ b_ih, const float* __restrict__ b_hh,
                            const float* __restrict__ Wi, const float* __restrict__ Wc, const float* __restrict__ Wo,
                            f16* __restrict__ Wpack, float* __restrict__ bsum, float* __restrict__ WT)
{
    int idx = blockIdx.x*256 + threadIdx.x;
    if (idx < 512*288){
        int j = idx / 288, k = idx % 288;
        float v = 0.f;
        if (k < 130) v = W_ih[j*130 + k];
        else if (k >= 160) v = W_hh[j*128 + (k-160)];
        Wpack[j*288 + k] = (f16)v;
    }
    if (idx < 512) bsum[idx] = b_ih[idx] + b_hh[idx];
    if (idx < 3*128*128){
        int w = idx >> 14, rem = idx & 16383, k = rem >> 7, u = rem & 127;
        const float* W = (w==0) ? Wi : (w==1) ? Wc : Wo;
        WT[idx] = W[u*128 + k];   // WT[w][k][u] = W[u][k]
    }
}

// ---------------- prep: length sort + per-stream sorted event lists ----------------
__device__ __forceinline__ void add_ev(int* et, int* es, int& n, int t, int slot, int len){
    if (t < 0 || t >= len) return;
    int p = n++;
    while (p > 0 && et[p-1] > t){ et[p] = et[p-1]; es[p] = es[p-1]; --p; }
    et[p] = t; es[p] = slot;
}

__global__ void sched_kernel(const int* __restrict__ len_t, const int* __restrict__ len_a, const int* __restrict__ len_f,
                             const int* __restrict__ sub_ta, const int* __restrict__ sub_tf,
                             const int* __restrict__ sub_a, const int* __restrict__ sub_f,
                             int* __restrict__ order, int* __restrict__ slen,
                             int* __restrict__ ev_t, int* __restrict__ ev_slot, int* __restrict__ nev)
{
    __shared__ int L[768];
    int s = threadIdx.x;              // 0..767, stream id = e*256 + b
    int e = s >> 8, b = s & 255;
    int len = (e==0) ? len_t[b] : (e==1) ? len_a[b] : len_f[b];
    L[s] = len;
    __syncthreads();
    int rank = 0;
    for (int i = 0; i < 768; ++i){
        int li = L[i];
        rank += (li > len) || (li == len && i < s);
    }
    order[rank] = s;                  // descending by length, bijective
    slen[s] = len;

    int et[NEV], es[NEV]; int n = 0;
    if (e == 0){
        for (int r = 0; r < 10; ++r){
            add_ev(et, es, n, sub_ta[b*10+r]-1, b*10+r,        len);
            add_ev(et, es, n, sub_tf[b*10+r]-1, 2560 + b*10+r, len);
        }
    } else if (e == 1){
        for (int r = 0; r < 10; ++r) add_ev(et, es, n, sub_a[b*10+r]-1, 5120 + b*10+r, len);
    } else {
        for (int r = 0; r < 10; ++r) add_ev(et, es, n, sub_f[b*10+r]-1, 7680 + b*10+r, len);
    }
    add_ev(et, es, n, len-1, 10240 + s, len);   // final hidden state
    nev[s] = n;
    for (int i = 0; i < n; ++i){ ev_t[s*NEV+i] = et[i]; ev_slot[s*NEV+i] = es[i]; }
}

// ---------------- main: 3 LSTM streams per block, weights resident in VGPRs as MFMA B-frags ----------------
__launch_bounds__(512, 2)
__global__ void lstm_kernel(const float* __restrict__ gps0, const float* __restrict__ gps1, const float* __restrict__ gps2,
                            const int* __restrict__ grid0, const int* __restrict__ grid1, const int* __restrict__ grid2,
                            const float* __restrict__ E,
                            const f16* __restrict__ Wpack, const float* __restrict__ bsum,
                            const int* __restrict__ order, const int* __restrict__ slen,
                            const int* __restrict__ ev_t, const int* __restrict__ ev_slot, const int* __restrict__ nev,
                            float* __restrict__ stash)
{
    __shared__ f16   A_s[16][ASTR];        // rows 0..2 = streams; k: [0,130)=x, [160,288)=h, rest 0
    __shared__ float gates_s[4][NG];
    __shared__ int   ev_t_s[3][NEV];
    __shared__ int   ev_slot_s[3][NEV];
    __shared__ int   idx_ring[3][4];

    const int tid  = threadIdx.x;
    const int lane = tid & 63;
    const int wv   = tid >> 6;
    const int bi   = blockIdx.x;

    const int s0 = order[bi], s1 = order[bi+256], s2 = order[bi+512];
    const int l0 = slen[s0], l1 = slen[s1], l2 = slen[s2];
    int maxlen = l0 > l1 ? l0 : l1; if (l2 > maxlen) maxlen = l2;

    // roles: tid<384 -> x-loader + nonlin (m = tid>>7, u = tid&127);
    // 384..389 -> gps loader; 390..392 -> grid-index loader
    int m_role = -1;
    if (tid < 384) m_role = tid >> 7;
    else if (tid < 390) m_role = (tid - 384) >> 1;
    else if (tid < 393) m_role = tid - 390;

    const float* gps_m = nullptr; const int* grid_m = nullptr;
    int len_m = 0, nev_m = 0;
    if (m_role >= 0){
        int sm = (m_role==0) ? s0 : (m_role==1) ? s1 : s2;
        int e = sm >> 8, b = sm & 255;
        gps_m  = ((e==0) ? gps0 : (e==1) ? gps1 : gps2) + (size_t)b * (TT*2);
        grid_m = ((e==0) ? grid0 : (e==1) ? grid1 : grid2) + (size_t)b * TT;
        len_m = (m_role==0) ? l0 : (m_role==1) ? l1 : l2;
        nev_m = nev[sm];
    }
    const int u = tid & 127;
    float bI=0.f, bF=0.f, bG=0.f, bO=0.f;
    if (tid < 384){ bI = bsum[u]; bF = bsum[128+u]; bG = bsum[256+u]; bO = bsum[384+u]; }

    if (tid < 72){
        int m = tid / NEV, i = tid % NEV;
        int sm = (m==0) ? s0 : (m==1) ? s1 : s2;
        ev_t_s[m][i]    = ev_t[sm*NEV + i];
        ev_slot_s[m][i] = ev_slot[sm*NEV + i];
    }

    for (int i = tid; i < 16*ASTR; i += 512) (&A_s[0][0])[i] = (f16)0.f;

    // resident weight fragments: wave wv owns gate columns [64*wv, 64*wv+64)
    f16x8 wfrag[4][9];
    {
        const int jr = (wv << 6) + (lane & 15);
        const int kg = (lane >> 4) << 3;
        #pragma unroll
        for (int nt = 0; nt < 4; ++nt)
            #pragma unroll
            for (int ks = 0; ks < 9; ++ks)
                wfrag[nt][ks] = *reinterpret_cast<const f16x8*>(Wpack + (size_t)(jr + (nt<<4)) * 288 + (ks<<5) + kg);
    }

    __syncthreads();
    if (tid >= 390 && tid < 393){
        idx_ring[m_role][0] = grid_m[0];
        idx_ring[m_role][1] = grid_m[1];
    }
    __syncthreads();
    // x_0 into A_s
    if (tid < 384){
        int i0 = idx_ring[m_role][0];
        float v = (i0 == 0) ? 0.f : E[(size_t)i0 * HH + u];
        A_s[m_role][u] = (f16)v;
    } else if (tid < 390){
        int c = (tid - 384) & 1;
        A_s[m_role][HH + c] = (f16)gps_m[c];
    }
    __syncthreads();

    float creg = 0.f;
    int evp = 0;

    for (int t = 0; t < maxlen; ++t){
        // phase a: issue prefetches for step t+1 (latency hides under MFMA + nonlin)
        float eval = 0.f, gval = 0.f; int gnext = 0;
        if (tid < 384){
            int idxn = idx_ring[m_role][(t+1) & 3];
            eval = (idxn == 0) ? 0.f : E[(size_t)idxn * HH + u];
        } else if (tid < 390){
            int tn1 = (t+1 < TT) ? t+1 : TT-1;
            gval = gps_m[(size_t)tn1*2 + ((tid-384)&1)];
        } else if (tid < 393){
            int tn2 = (t+2 < TT) ? t+2 : TT-1;
            gnext = grid_m[tn2];
        }

        // phase b: gates = [x_t | h_{t-1}] . W^T   (M=16, rows 0..2 live)
        f16x8 a[9];
        {
            const int r  = lane & 15;
            const int kg = (lane >> 4) << 3;
            #pragma unroll
            for (int ks = 0; ks < 9; ++ks)
                a[ks] = *reinterpret_cast<const f16x8*>(&A_s[r][(ks<<5) + kg]);
        }
        f32x4 ac0 = {0.f,0.f,0.f,0.f}, ac1 = ac0, ac2 = ac0, ac3 = ac0;
        #pragma unroll
        for (int ks = 0; ks < 9; ++ks){
            ac0 = __builtin_amdgcn_mfma_f32_16x16x32_f16(a[ks], wfrag[0][ks], ac0, 0, 0, 0);
            ac1 = __builtin_amdgcn_mfma_f32_16x16x32_f16(a[ks], wfrag[1][ks], ac1, 0, 0, 0);
            ac2 = __builtin_amdgcn_mfma_f32_16x16x32_f16(a[ks], wfrag[2][ks], ac2, 0, 0, 0);
            ac3 = __builtin_amdgcn_mfma_f32_16x16x32_f16(a[ks], wfrag[3][ks], ac3, 0, 0, 0);
        }
        // D layout: col = lane&15, row = (lane>>4)*4 + reg -> lanes 0..15 hold rows(streams) 0..3
        if (lane < 16){
            int j = (wv << 6) + lane;
            #pragma unroll
            for (int r = 0; r < 4; ++r){
                gates_s[r][j]      = ac0[r];
                gates_s[r][j + 16] = ac1[r];
                gates_s[r][j + 32] = ac2[r];
                gates_s[r][j + 48] = ac3[r];
            }
        }
        __syncthreads();   // B1

        // phase d: nonlinearity (fp32), h deposit, event stashes
        if (tid < 384 && t < len_m){
            float gi = gates_s[m_role][u]       + bI;
            float gf = gates_s[m_role][128 + u] + bF;
            float gg = gates_s[m_role][256 + u] + bG;
            float go = gates_s[m_role][384 + u] + bO;
            float si = sigm(gi), sf = sigm(gf), so = sigm(go);
            float tg = tanh_f(gg);
            float cn = sf * creg + si * tg;
            creg = cn;
            float h = so * tanh_f(cn);
            A_s[m_role][160 + u] = (f16)h;
            while (evp < nev_m && ev_t_s[m_role][evp] == t){
                stash[(size_t)ev_slot_s[m_role][evp] * HH + u] = h;
                ++evp;
            }
        }
        // phase e: deposit prefetched x_{t+1} / ring update
        if (tid < 384){
            A_s[m_role][u] = (f16)eval;
        } else if (tid < 390){
            A_s[m_role][HH + ((tid-384)&1)] = (f16)gval;
        } else if (tid < 393){
            idx_ring[m_role][(t+2) & 3] = gnext;
        }
        __syncthreads();   // B2
    }
}

// ---------------- fsim applied in-place on the stash (fp32, LDS-staged transposed weights) ----------------
__global__ void fsim_kernel(float* __restrict__ stash, const float* __restrict__ WT,
                            const float* __restrict__ bi, const float* __restrict__ bc, const float* __restrict__ bo,
                            const int* __restrict__ sub_ta, const int* __restrict__ sub_tf,
                            const int* __restrict__ sub_a, const int* __restrict__ sub_f,
                            const int* __restrict__ len_t, const int* __restrict__ len_a, const int* __restrict__ len_f)
{
    __shared__ float h_s[64][HH];
    __shared__ float w_s[3][32][HH];
    const int tid = threadIdx.x;
    const int base = blockIdx.x * 64;

    for (int i = tid; i < 64*HH; i += 256){
        int v = i >> 7, k = i & 127;
        int row = base + v;
        bool valid = true;
        if (row < 10240){
            int g = row / 2560, rr = row % 2560, b = rr / 10;
            int sub, len;
            if (g == 0){ sub = sub_ta[rr]; len = len_t[b]; }
            else if (g == 1){ sub = sub_tf[rr]; len = len_t[b]; }
            else if (g == 2){ sub = sub_a[rr]; len = len_a[b]; }
            else { sub = sub_f[rr]; len = len_f[b]; }
            valid = (sub - 1) < len;    // y is zero past length
        }
        h_s[v][k] = valid ? stash[(size_t)row * HH + k] : 0.f;
    }
    __syncthreads();

    const int uu = tid & 127;
    const int vb = (tid >> 7) << 5;
    float aI[32], aC[32], aO[32];
    #pragma unroll
    for (int v = 0; v < 32; ++v){ aI[v]=0.f; aC[v]=0.f; aO[v]=0.f; }

    for (int kc = 0; kc < 4; ++kc){
        for (int i = tid; i < 3*32*HH; i += 256){
            int w = i >> 12, rem = i & 4095, kk = rem >> 7, u2 = rem & 127;
            w_s[w][kk][u2] = WT[(size_t)w*16384 + (size_t)(kc*32 + kk)*HH + u2];
        }
        __syncthreads();
        for (int kk = 0; kk < 32; ++kk){
            float wi = w_s[0][kk][uu], wc = w_s[1][kk][uu], wo = w_s[2][kk][uu];
            #pragma unroll
            for (int v = 0; v < 32; ++v){
                float h = h_s[vb + v][kc*32 + kk];
                aI[v] = fmaf(h, wi, aI[v]);
                aC[v] = fmaf(h, wc, aC[v]);
                aO[v] = fmaf(h, wo, aO[v]);
            }
        }
        __syncthreads();
    }
    float BI = bi[uu], BC = bc[uu], BO = bo[uu];
    #pragma unroll
    for (int v = 0; v < 32; ++v){
        float C   = sigm(aI[v] + BI) * tanh_f(aC[v] + BC);
        float out = sigm(aO[v] + BO) * tanh_f(C) + h_s[vb + v][uu];
        stash[(size_t)(base + vb + v) * HH + uu] = out;
    }
}

// ---------------- distances: out = exp(-||u - v||) ----------------
__global__ void dist_kernel(const float* __restrict__ fs, float* __restrict__ out)
{
    int gid = blockIdx.x * 256 + threadIdx.x;
    int pair = gid >> 6, ln = gid & 63;
    if (pair >= 5632) return;
    int ia, ib;
    if (pair < 256){ ia = 10240 + pair; ib = 10240 + 256 + pair; }
    else if (pair < 512){ int j = pair - 256; ia = 10240 + j; ib = 10240 + 512 + j; }
    else if (pair < 3072){ int j = pair - 512; ia = j; ib = 5120 + j; }
    else { int j = pair - 3072; ia = 2560 + j; ib = 7680 + j; }
    float d = 0.f;
    #pragma unroll
    for (int k = 0; k < 2; ++k){
        int kk = ln + k*64;
        float df = fs[(size_t)ia*HH + kk] - fs[(size_t)ib*HH + kk];
        d = fmaf(df, df, d);
    }
    #pragma unroll
    for (int off = 32; off > 0; off >>= 1) d += __shfl_xor(d, off);
    if (ln == 0) out[pair] = __expf(-sqrtf(d));
}

extern "C" void kernel_launch(void* const* d_in, const int* in_sizes, int n_in,
                              void* d_out, int out_size, void* d_ws, size_t ws_size,
                              hipStream_t stream)
{
    (void)in_sizes; (void)n_in; (void)out_size; (void)ws_size;
    const float* traj_gps = (const float*)d_in[0];
    const int*   traj_grid = (const int*)d_in[2];
    const int*   traj_len = (const int*)d_in[4];
    const int*   sub_ta = (const int*)d_in[5];
    const int*   sub_tf = (const int*)d_in[6];
    const float* anc_gps = (const float*)d_in[7];
    const int*   anc_grid = (const int*)d_in[9];
    const int*   anc_len = (const int*)d_in[11];
    const int*   sub_a = (const int*)d_in[12];
    const float* far_gps = (const float*)d_in[13];
    const int*   far_grid = (const int*)d_in[15];
    const int*   far_len = (const int*)d_in[17];
    const int*   sub_f = (const int*)d_in[18];
    const float* E    = (const float*)d_in[19];
    const float* W_ih = (const float*)d_in[20];
    const float* W_hh = (const float*)d_in[21];
    const float* b_ih = (const float*)d_in[22];
    const float* b_hh = (const float*)d_in[23];
    const float* Wi = (const float*)d_in[24];
    const float* bi = (const float*)d_in[25];
    const float* Wc = (const float*)d_in[26];
    const float* bc = (const float*)d_in[27];
    const float* Wo = (const float*)d_in[28];
    const float* bo = (const float*)d_in[29];

    char* p = (char*)d_ws;
    f16* Wpack   = (f16*)p;   p += (size_t)512*288*2;
    float* bsum  = (float*)p; p += 512*4;
    float* WT    = (float*)p; p += (size_t)3*128*128*4;
    int* order   = (int*)p;   p += 768*4;
    int* slen    = (int*)p;   p += 768*4;
    int* ev_t    = (int*)p;   p += 768*NEV*4;
    int* ev_slot = (int*)p;   p += 768*NEV*4;
    int* nev     = (int*)p;   p += 768*4;
    float* stash = (float*)p; p += (size_t)11008*128*4;   // also reused as fsim output

    pack_kernel<<<576, 256, 0, stream>>>(W_ih, W_hh, b_ih, b_hh, Wi, Wc, Wo, Wpack, bsum, WT);
    sched_kernel<<<1, 768, 0, stream>>>(traj_len, anc_len, far_len, sub_ta, sub_tf, sub_a, sub_f,
                                        order, slen, ev_t, ev_slot, nev);
    lstm_kernel<<<256, 512, 0, stream>>>(traj_gps, anc_gps, far_gps, traj_grid, anc_grid, far_grid,
                                         E, Wpack, bsum, order, slen, ev_t, ev_slot, nev, stash);
    fsim_kernel<<<172, 256, 0, stream>>>(stash, WT, bi, bc, bo, sub_ta, sub_tf, sub_a, sub_f,
                                         traj_len, anc_len, far_len);
    dist_kernel<<<1408, 256, 0, stream>>>(stash, (float*)d_out);
}

// Round 2
// 1463.491 us; speedup vs baseline: 1.2909x; 1.2909x over previous
//
#include <hip/hip_runtime.h>
#include <math.h>

typedef _Float16 f16;
typedef _Float16 f16x8 __attribute__((ext_vector_type(8)));
typedef float f32x4 __attribute__((ext_vector_type(4)));

#define TT 1024
#define HH 128
#define SROW 336   // halves per A_s row: 168 dwords -> start bank 8r, 2 addrs/bank-group (free)
#define NEV 24

__device__ __forceinline__ float sigm(float x){ return 1.f/(1.f + __expf(-x)); }
__device__ __forceinline__ float tanh_f(float x){
    float ax = fabsf(x);
    float e = __expf(-2.f*ax);
    float r = (1.f - e)/(1.f + e);
    return (x < 0.f) ? -r : r;
}

// ---------------- prep: pack LSTM weights (f16, K-padded) + bias sum + transposed fsim weights ----------------
__global__ void pack_kernel(const float* __restrict__ W_ih, const float* __restrict__ W_hh,
                            const float* __restrict__ b_ih, const float* __restrict__ b_hh,
                            const float* __restrict__ Wi, const float* __restrict__ Wc, const float* __restrict__ Wo,
                            f16* __restrict__ Wpack, float* __restrict__ bsum, float* __restrict__ WT)
{
    int idx = blockIdx.x*256 + threadIdx.x;
    if (idx < 512*288){
        int j = idx / 288, k = idx % 288;
        float v = 0.f;
        if (k < 130) v = W_ih[j*130 + k];
        else if (k >= 160) v = W_hh[j*128 + (k-160)];
        Wpack[j*288 + k] = (f16)v;
    }
    if (idx < 512) bsum[idx] = b_ih[idx] + b_hh[idx];
    if (idx < 3*128*128){
        int w = idx >> 14, rem = idx & 16383, k = rem >> 7, u = rem & 127;
        const float* W = (w==0) ? Wi : (w==1) ? Wc : Wo;
        WT[idx] = W[u*128 + k];   // WT[w][k][u] = W[u][k]
    }
}

// ---------------- prep: length sort + per-stream sorted event lists ----------------
__device__ __forceinline__ void add_ev(int* et, int* es, int& n, int t, int slot, int len){
    if (t < 0 || t >= len) return;
    int p = n++;
    while (p > 0 && et[p-1] > t){ et[p] = et[p-1]; es[p] = es[p-1]; --p; }
    et[p] = t; es[p] = slot;
}

__global__ void sched_kernel(const int* __restrict__ len_t, const int* __restrict__ len_a, const int* __restrict__ len_f,
                             const int* __restrict__ sub_ta, const int* __restrict__ sub_tf,
                             const int* __restrict__ sub_a, const int* __restrict__ sub_f,
                             int* __restrict__ order, int* __restrict__ slen,
                             int* __restrict__ ev_t, int* __restrict__ ev_slot, int* __restrict__ nev)
{
    __shared__ int L[768];
    int s = threadIdx.x;              // 0..767, stream id = e*256 + b
    int e = s >> 8, b = s & 255;
    int len = (e==0) ? len_t[b] : (e==1) ? len_a[b] : len_f[b];
    L[s] = len;
    __syncthreads();
    int rank = 0;
    for (int i = 0; i < 768; ++i){
        int li = L[i];
        rank += (li > len) || (li == len && i < s);
    }
    order[rank] = s;                  // descending by length, bijective
    slen[s] = len;

    int et[NEV], es[NEV]; int n = 0;
    if (e == 0){
        for (int r = 0; r < 10; ++r){
            add_ev(et, es, n, sub_ta[b*10+r]-1, b*10+r,        len);
            add_ev(et, es, n, sub_tf[b*10+r]-1, 2560 + b*10+r, len);
        }
    } else if (e == 1){
        for (int r = 0; r < 10; ++r) add_ev(et, es, n, sub_a[b*10+r]-1, 5120 + b*10+r, len);
    } else {
        for (int r = 0; r < 10; ++r) add_ev(et, es, n, sub_f[b*10+r]-1, 7680 + b*10+r, len);
    }
    add_ev(et, es, n, len-1, 10240 + s, len);   // final hidden state
    nev[s] = n;
    for (int i = 0; i < n; ++i){ ev_t[s*NEV+i] = et[i]; ev_slot[s*NEV+i] = es[i]; }
}

// ---------------- main LSTM: 3 streams/block, in-register gates+nonlin, 1 lgkm-only barrier/step ----------------
__launch_bounds__(512, 2)
__global__ void lstm_kernel(const float* __restrict__ gps0, const float* __restrict__ gps1, const float* __restrict__ gps2,
                            const int* __restrict__ grid0, const int* __restrict__ grid1, const int* __restrict__ grid2,
                            const float* __restrict__ E,
                            const f16* __restrict__ Wpack, const float* __restrict__ bsum,
                            const int* __restrict__ order, const int* __restrict__ slen,
                            const int* __restrict__ ev_t, const int* __restrict__ ev_slot, const int* __restrict__ nev,
                            float* __restrict__ stash)
{
    __shared__ f16 A_s[2][4][SROW];     // double-buffered; phys rows 0..2 = streams, row 3 = zero
    __shared__ int ring_s[3][8];        // grid-index ring, 2-step-deep prefetch
    __shared__ int ev_t_s[3][NEV];
    __shared__ int ev_sl_s[3][NEV];

    const int tid  = threadIdx.x;
    const int lane = tid & 63;
    const int wv   = tid >> 6;
    const int q    = lane >> 4;         // lane quarter: 0..2 = nonlin stream q, 3 = staging duty
    const int li   = lane & 15;
    const int u    = (wv << 4) + li;    // unit index 0..127
    const int bi   = blockIdx.x;

    const int s0 = order[bi], s1 = order[bi+256], s2 = order[bi+512];
    const int l0 = slen[s0], l1 = slen[s1], l2 = slen[s2];
    int maxlen = l0 > l1 ? l0 : l1; if (l2 > maxlen) maxlen = l2;

    // ---- init LDS ----
    for (int i = tid; i < 2*4*SROW; i += 512) (&A_s[0][0][0])[i] = (f16)0.f;
    if (tid < 72){
        int m = tid / NEV, i = tid % NEV;
        int sm = (m==0) ? s0 : (m==1) ? s1 : s2;
        ev_t_s[m][i]  = ev_t[sm*NEV + i];
        ev_sl_s[m][i] = ev_slot[sm*NEV + i];
    }

    // ---- resident weight fragments: wave wv owns units [16wv,16wv+16), nt tile = gate ----
    f16x8 wI[9], wF[9], wG[9], wO[9];
    {
        const int kg = q << 3;
        #pragma unroll
        for (int ks = 0; ks < 9; ++ks){
            const int koff = ks*32 + kg;
            wI[ks] = *reinterpret_cast<const f16x8*>(Wpack + (size_t)(  0 + (wv<<4) + li) * 288 + koff);
            wF[ks] = *reinterpret_cast<const f16x8*>(Wpack + (size_t)(128 + (wv<<4) + li) * 288 + koff);
            wG[ks] = *reinterpret_cast<const f16x8*>(Wpack + (size_t)(256 + (wv<<4) + li) * 288 + koff);
            wO[ks] = *reinterpret_cast<const f16x8*>(Wpack + (size_t)(384 + (wv<<4) + li) * 288 + koff);
        }
    }

    // ---- per-role scalar state ----
    float bI_r=0.f, bF_r=0.f, bG_r=0.f, bO_r=0.f, creg=0.f, hreg=0.f;
    int len_q=0, nev_q=0, evp=0, next_t=1<<30;
    if (q < 3){
        int sq = (q==0)?s0:(q==1)?s1:s2;
        len_q = (q==0)?l0:(q==1)?l1:l2;
        nev_q = nev[sq];
        bI_r = bsum[u]; bF_r = bsum[128+u]; bG_r = bsum[256+u]; bO_r = bsum[384+u];
    }

    float ev_cur0=0.f, ev_cur1=0.f, ev_cur2=0.f, gp_cur=0.f;
    int gd_cur=0;
    const float* gps_p = nullptr;
    const int*   grid_p = nullptr;

    __syncthreads();   // zero-init / ev lists visible

    // ---- prologue: x_0 deposit, x_1 in regs, ring/gps primed ----
    if (q == 3){
        const int e0=s0>>8,b0=s0&255, e1=s1>>8,b1=s1&255, e2=s2>>8,b2=s2&255;
        const int* g0p = ((e0==0)?grid0:(e0==1)?grid1:grid2) + (size_t)b0*TT;
        const int* g1p = ((e1==0)?grid0:(e1==1)?grid1:grid2) + (size_t)b1*TT;
        const int* g2p = ((e2==0)?grid0:(e2==1)?grid1:grid2) + (size_t)b2*TT;
        int ia0=g0p[0], ib0=g0p[1];
        int ia1=g1p[0], ib1=g1p[1];
        int ia2=g2p[0], ib2=g2p[1];
        A_s[0][0][u] = (f16)((ia0==0)?0.f:E[(size_t)ia0*HH+u]);
        A_s[0][1][u] = (f16)((ia1==0)?0.f:E[(size_t)ia1*HH+u]);
        A_s[0][2][u] = (f16)((ia2==0)?0.f:E[(size_t)ia2*HH+u]);
        ev_cur0 = (ib0==0)?0.f:E[(size_t)ib0*HH+u];
        ev_cur1 = (ib1==0)?0.f:E[(size_t)ib1*HH+u];
        ev_cur2 = (ib2==0)?0.f:E[(size_t)ib2*HH+u];
        if (wv == 1 && li < 3){
            grid_p = (li==0)?g0p:(li==1)?g1p:g2p;
            ring_s[li][2] = grid_p[2];
            gd_cur = grid_p[3];
        }
        if (wv == 0 && li < 6){
            int m = li>>1, c = li&1;
            int sm = (m==0)?s0:(m==1)?s1:s2;
            int em = sm>>8, bm = sm&255;
            gps_p = ((em==0)?gps0:(em==1)?gps1:gps2) + (size_t)bm*(TT*2);
            A_s[0][m][128+c] = (f16)gps_p[c];
            gp_cur = gps_p[2+c];
        }
    } else {
        if (nev_q > 0) next_t = ev_t_s[q][0];
    }
    __syncthreads();

    // ---- main loop: ONE lgkm-only barrier per step ----
    for (int t = 0; t < maxlen; ++t){
        const int p  = t & 1;
        const int p1 = p ^ 1;

        // Q3: deposit x_{t+1} (loaded last step), issue prefetch for x_{t+2}
        if (q == 3){
            A_s[p1][0][u] = (f16)ev_cur0;
            A_s[p1][1][u] = (f16)ev_cur1;
            A_s[p1][2][u] = (f16)ev_cur2;
            if (wv == 0 && li < 6) A_s[p1][li>>1][128 + (li&1)] = (f16)gp_cur;
            if (wv == 1 && li < 3) ring_s[li][(t+3)&7] = gd_cur;
            int i0 = ring_s[0][(t+2)&7];
            int i1 = ring_s[1][(t+2)&7];
            int i2 = ring_s[2][(t+2)&7];
            ev_cur0 = (i0==0)?0.f:E[(size_t)i0*HH+u];
            ev_cur1 = (i1==0)?0.f:E[(size_t)i1*HH+u];
            ev_cur2 = (i2==0)?0.f:E[(size_t)i2*HH+u];
            if (wv == 0 && li < 6) gp_cur = gps_p[(size_t)((t+2<TT)?t+2:TT-1)*2 + (li&1)];
            if (wv == 1 && li < 3) gd_cur = grid_p[(t+4<TT)?t+4:TT-1];
        }

        // MFMA: gates = [x_t | h_{t-1}] . W^T ; rows 4..15 alias phys rows 0..3 (broadcast reads)
        f32x4 acI = {0.f,0.f,0.f,0.f}, acF = acI, acG = acI, acO = acI;
        {
            const f16* Arow = &A_s[p][lane&3][q<<3];
            #pragma unroll
            for (int ks = 0; ks < 9; ++ks){
                f16x8 av = *reinterpret_cast<const f16x8*>(Arow + ks*32);
                acI = __builtin_amdgcn_mfma_f32_16x16x32_f16(av, wI[ks], acI, 0, 0, 0);
                acF = __builtin_amdgcn_mfma_f32_16x16x32_f16(av, wF[ks], acF, 0, 0, 0);
                acG = __builtin_amdgcn_mfma_f32_16x16x32_f16(av, wG[ks], acG, 0, 0, 0);
                acO = __builtin_amdgcn_mfma_f32_16x16x32_f16(av, wO[ks], acO, 0, 0, 0);
            }
        }

        // nonlin fully in-register: quarter q processes stream q (reg q), unit u
        if (q < 3){
            float gI = (q==0) ? acI[0] : (q==1) ? acI[1] : acI[2];
            float gF = (q==0) ? acF[0] : (q==1) ? acF[1] : acF[2];
            float gG = (q==0) ? acG[0] : (q==1) ? acG[1] : acG[2];
            float gO = (q==0) ? acO[0] : (q==1) ? acO[1] : acO[2];
            if (t < len_q){
                float si = sigm(gI + bI_r);
                float sf = sigm(gF + bF_r);
                float so = sigm(gO + bO_r);
                float tg = tanh_f(gG + bG_r);
                creg = sf * creg + si * tg;
                hreg = so * tanh_f(creg);
                while (t == next_t){
                    stash[(size_t)ev_sl_s[q][evp]*HH + u] = hreg;
                    ++evp;
                    next_t = (evp < nev_q) ? ev_t_s[q][evp] : (1<<30);
                }
            }
            A_s[p1][q][160 + u] = (f16)hreg;   // frozen past len
        }

        asm volatile("s_waitcnt lgkmcnt(0)" ::: "memory");
        __builtin_amdgcn_s_barrier();
        asm volatile("" ::: "memory");
    }
}

// ---------------- fsim applied in-place on the stash (fp32, LDS-staged transposed weights) ----------------
__global__ void fsim_kernel(float* __restrict__ stash, const float* __restrict__ WT,
                            const float* __restrict__ bi, const float* __restrict__ bc, const float* __restrict__ bo,
                            const int* __restrict__ sub_ta, const int* __restrict__ sub_tf,
                            const int* __restrict__ sub_a, const int* __restrict__ sub_f,
                            const int* __restrict__ len_t, const int* __restrict__ len_a, const int* __restrict__ len_f)
{
    __shared__ float h_s[64][HH];
    __shared__ float w_s[3][32][HH];
    const int tid = threadIdx.x;
    const int base = blockIdx.x * 64;

    for (int i = tid; i < 64*HH; i += 256){
        int v = i >> 7, k = i & 127;
        int row = base + v;
        bool valid = true;
        if (row < 10240){
            int g = row / 2560, rr = row % 2560, b = rr / 10;
            int sub, len;
            if (g == 0){ sub = sub_ta[rr]; len = len_t[b]; }
            else if (g == 1){ sub = sub_tf[rr]; len = len_t[b]; }
            else if (g == 2){ sub = sub_a[rr]; len = len_a[b]; }
            else { sub = sub_f[rr]; len = len_f[b]; }
            valid = (sub - 1) < len;    // y is zero past length
        }
        h_s[v][k] = valid ? stash[(size_t)row * HH + k] : 0.f;
    }
    __syncthreads();

    const int uu = tid & 127;
    const int vb = (tid >> 7) << 5;
    float aI[32], aC[32], aO[32];
    #pragma unroll
    for (int v = 0; v < 32; ++v){ aI[v]=0.f; aC[v]=0.f; aO[v]=0.f; }

    for (int kc = 0; kc < 4; ++kc){
        for (int i = tid; i < 3*32*HH; i += 256){
            int w = i >> 12, rem = i & 4095, kk = rem >> 7, u2 = rem & 127;
            w_s[w][kk][u2] = WT[(size_t)w*16384 + (size_t)(kc*32 + kk)*HH + u2];
        }
        __syncthreads();
        for (int kk = 0; kk < 32; ++kk){
            float wi = w_s[0][kk][uu], wc = w_s[1][kk][uu], wo = w_s[2][kk][uu];
            #pragma unroll
            for (int v = 0; v < 32; ++v){
                float h = h_s[vb + v][kc*32 + kk];
                aI[v] = fmaf(h, wi, aI[v]);
                aC[v] = fmaf(h, wc, aC[v]);
                aO[v] = fmaf(h, wo, aO[v]);
            }
        }
        __syncthreads();
    }
    float BI = bi[uu], BC = bc[uu], BO = bo[uu];
    #pragma unroll
    for (int v = 0; v < 32; ++v){
        float C   = sigm(aI[v] + BI) * tanh_f(aC[v] + BC);
        float out = sigm(aO[v] + BO) * tanh_f(C) + h_s[vb + v][uu];
        stash[(size_t)(base + vb + v) * HH + uu] = out;
    }
}

// ---------------- distances: out = exp(-||u - v||) ----------------
__global__ void dist_kernel(const float* __restrict__ fs, float* __restrict__ out)
{
    int gid = blockIdx.x * 256 + threadIdx.x;
    int pair = gid >> 6, ln = gid & 63;
    if (pair >= 5632) return;
    int ia, ib;
    if (pair < 256){ ia = 10240 + pair; ib = 10240 + 256 + pair; }
    else if (pair < 512){ int j = pair - 256; ia = 10240 + j; ib = 10240 + 512 + j; }
    else if (pair < 3072){ int j = pair - 512; ia = j; ib = 5120 + j; }
    else { int j = pair - 3072; ia = 2560 + j; ib = 7680 + j; }
    float d = 0.f;
    #pragma unroll
    for (int k = 0; k < 2; ++k){
        int kk = ln + k*64;
        float df = fs[(size_t)ia*HH + kk] - fs[(size_t)ib*HH + kk];
        d = fmaf(df, df, d);
    }
    #pragma unroll
    for (int off = 32; off > 0; off >>= 1) d += __shfl_xor(d, off);
    if (ln == 0) out[pair] = __expf(-sqrtf(d));
}

extern "C" void kernel_launch(void* const* d_in, const int* in_sizes, int n_in,
                              void* d_out, int out_size, void* d_ws, size_t ws_size,
                              hipStream_t stream)
{
    (void)in_sizes; (void)n_in; (void)out_size; (void)ws_size;
    const float* traj_gps = (const float*)d_in[0];
    const int*   traj_grid = (const int*)d_in[2];
    const int*   traj_len = (const int*)d_in[4];
    const int*   sub_ta = (const int*)d_in[5];
    const int*   sub_tf = (const int*)d_in[6];
    const float* anc_gps = (const float*)d_in[7];
    const int*   anc_grid = (const int*)d_in[9];
    const int*   anc_len = (const int*)d_in[11];
    const int*   sub_a = (const int*)d_in[12];
    const float* far_gps = (const float*)d_in[13];
    const int*   far_grid = (const int*)d_in[15];
    const int*   far_len = (const int*)d_in[17];
    const int*   sub_f = (const int*)d_in[18];
    const float* E    = (const float*)d_in[19];
    const float* W_ih = (const float*)d_in[20];
    const float* W_hh = (const float*)d_in[21];
    const float* b_ih = (const float*)d_in[22];
    const float* b_hh = (const float*)d_in[23];
    const float* Wi = (const float*)d_in[24];
    const float* bi = (const float*)d_in[25];
    const float* Wc = (const float*)d_in[26];
    const float* bc = (const float*)d_in[27];
    const float* Wo = (const float*)d_in[28];
    const float* bo = (const float*)d_in[29];

    char* p = (char*)d_ws;
    f16* Wpack   = (f16*)p;   p += (size_t)512*288*2;
    float* bsum  = (float*)p; p += 512*4;
    float* WT    = (float*)p; p += (size_t)3*128*128*4;
    int* order   = (int*)p;   p += 768*4;
    int* slen    = (int*)p;   p += 768*4;
    int* ev_t    = (int*)p;   p += 768*NEV*4;
    int* ev_slot = (int*)p;   p += 768*NEV*4;
    int* nev     = (int*)p;   p += 768*4;
    float* stash = (float*)p; p += (size_t)11008*128*4;   // also reused as fsim output

    pack_kernel<<<576, 256, 0, stream>>>(W_ih, W_hh, b_ih, b_hh, Wi, Wc, Wo, Wpack, bsum, WT);
    sched_kernel<<<1, 768, 0, stream>>>(traj_len, anc_len, far_len, sub_ta, sub_tf, sub_a, sub_f,
                                        order, slen, ev_t, ev_slot, nev);
    lstm_kernel<<<256, 512, 0, stream>>>(traj_gps, anc_gps, far_gps, traj_grid, anc_grid, far_grid,
                                         E, Wpack, bsum, order, slen, ev_t, ev_slot, nev, stash);
    fsim_kernel<<<172, 256, 0, stream>>>(stash, WT, bi, bc, bo, sub_ta, sub_tf, sub_a, sub_f,
                                         traj_len, anc_len, far_len);
    dist_kernel<<<1408, 256, 0, stream>>>(stash, (float*)d_out);
}